// Round 7
// baseline (374.729 us; speedup 1.0000x reference)
//
#include <hip/hip_runtime.h>

// HierarchicalGraphSAGE bf16-MFMA version, R7.
// N=50000, E=800000, D=128, OUT=64, G=64.
//
//  R7 changes vs R6:
//   - k_agg + k_sage fused into k_layer: per-64-node block, gather-aggregate
//     directly into the LDS A-tile (wave = 16 nodes, 4-deep pipelined loads),
//     stage h rows, one barrier, MFMA. Kills 25.6MB/layer of agg round-trip
//     traffic + the grid-wide serialization between gather and GEMM.
//   - binned[] packed to 4B/edge: src in bits 0..15, dst&127 in bits 16..22.

typedef __bf16 bf16x8 __attribute__((ext_vector_type(8)));
typedef float f32x4 __attribute__((ext_vector_type(4)));

#define BINB 160          // binning blocks
#define NBMAX 512         // max buckets (N <= 65536)

static __device__ __forceinline__ float bf2f(unsigned short u) {
    union { unsigned u; float f; } c; c.u = (unsigned)u << 16; return c.f;
}
static __device__ __forceinline__ unsigned short f2bf(float f) {
    unsigned u = __builtin_bit_cast(unsigned, f);
    return (unsigned short)((u + 0x7fffu + ((u >> 16) & 1u)) >> 16);
}

// ---------------- bucket counting sort ----------------
__global__ __launch_bounds__(256) void k_bincount(
    const int* __restrict__ dst, int* __restrict__ cnt_mat, int E, int nb, int epb)
{
    __shared__ int lc[NBMAX];
    for (int i = threadIdx.x; i < nb; i += 256) lc[i] = 0;
    __syncthreads();
    int b0 = blockIdx.x * epb;
    int b1 = min(b0 + epb, E);
    for (int i = b0 + threadIdx.x; i < b1; i += 256)
        atomicAdd(&lc[dst[i] >> 7], 1);
    __syncthreads();
    for (int i = threadIdx.x; i < nb; i += 256)
        cnt_mat[i * BINB + blockIdx.x] = lc[i];
}

__global__ __launch_bounds__(256) void k_binscatter(
    const int* __restrict__ ei, const int* __restrict__ off_mat,
    unsigned* __restrict__ binned, int E, int nb, int epb)
{
    __shared__ int lofs[NBMAX];
    __shared__ int lcnt[NBMAX];
    for (int i = threadIdx.x; i < nb; i += 256) {
        lofs[i] = off_mat[i * BINB + blockIdx.x];
        lcnt[i] = 0;
    }
    __syncthreads();
    int b0 = blockIdx.x * epb;
    int b1 = min(b0 + epb, E);
    for (int i = b0 + threadIdx.x; i < b1; i += 256) {
        int s = ei[i];
        int d = ei[E + i];
        int b = d >> 7;
        int r = atomicAdd(&lcnt[b], 1);
        binned[lofs[b] + r] = (unsigned)s | ((unsigned)(d & 127) << 16);
    }
}

// Per-node counts from the bucket's contiguous binned range (LDS atomics).
__global__ __launch_bounds__(256) void k_hist2(
    const unsigned* __restrict__ binned, const int* __restrict__ off_mat,
    int* __restrict__ counts, int E, int nb, int n)
{
    __shared__ int lc[128];
    int b = blockIdx.x;
    if (threadIdx.x < 128) lc[threadIdx.x] = 0;
    __syncthreads();
    int bs = off_mat[b * BINB];
    int be = (b == nb - 1) ? E : off_mat[(b + 1) * BINB];
    for (int i = bs + threadIdx.x; i < be; i += 256)
        atomicAdd(&lc[(binned[i] >> 16) & 127], 1);
    __syncthreads();
    int node = (b << 7) + threadIdx.x;
    if (threadIdx.x < 128 && node < n) counts[node] = lc[threadIdx.x];
}

// Fine scatter: slot counters in LDS, csr writes confined to bucket range.
__global__ __launch_bounds__(256) void k_fillfine(
    const unsigned* __restrict__ binned, const int* __restrict__ off_mat,
    const int* __restrict__ starts, int* __restrict__ csr_src, int E, int nb, int n)
{
    __shared__ int lpos[128];
    int b = blockIdx.x;
    int node0 = b << 7;
    if (threadIdx.x < 128) {
        int node = node0 + threadIdx.x;
        lpos[threadIdx.x] = (node < n) ? starts[node] : 0;
    }
    __syncthreads();
    int bs = off_mat[b * BINB];
    int be = (b == nb - 1) ? E : off_mat[(b + 1) * BINB];
    for (int i = bs + threadIdx.x; i < be; i += 256) {
        unsigned e = binned[i];
        int slot = atomicAdd(&lpos[(e >> 16) & 127], 1);
        csr_src[slot] = (int)(e & 0xffffu);
    }
}

// ---------------- hierarchical scan ----------------
__global__ __launch_bounds__(256) void k_scan1(
    const int* __restrict__ counts, int* __restrict__ bsum, int n)
{
    __shared__ int s[4];
    int i = blockIdx.x * 256 + threadIdx.x;
    int v = (i < n) ? counts[i] : 0;
#pragma unroll
    for (int off = 1; off < 64; off <<= 1) v += __shfl_xor(v, off);
    if ((threadIdx.x & 63) == 0) s[threadIdx.x >> 6] = v;
    __syncthreads();
    if (threadIdx.x == 0) bsum[blockIdx.x] = s[0] + s[1] + s[2] + s[3];
}

__global__ __launch_bounds__(256) void k_scan2(
    const int* __restrict__ bsum, int* __restrict__ boff, int nb, int* __restrict__ total_out)
{
    __shared__ int s[256];
    int t = threadIdx.x;
    int v = (t < nb) ? bsum[t] : 0;
    s[t] = v;
    __syncthreads();
#pragma unroll
    for (int off = 1; off < 256; off <<= 1) {
        int u = (t >= off) ? s[t - off] : 0;
        __syncthreads();
        s[t] += u;
        __syncthreads();
    }
    if (t < nb) boff[t] = s[t] - v;
    if (t == nb - 1) *total_out = s[t];
}

__global__ __launch_bounds__(256) void k_scan3m(
    const int* __restrict__ counts, const int* __restrict__ boff,
    int* __restrict__ starts, int n)
{
    __shared__ int s[256];
    int t = threadIdx.x;
    int i = blockIdx.x * 256 + t;
    int v = (i < n) ? counts[i] : 0;
    s[t] = v;
    __syncthreads();
#pragma unroll
    for (int off = 1; off < 256; off <<= 1) {
        int u = (t >= off) ? s[t - off] : 0;
        __syncthreads();
        s[t] += u;
        __syncthreads();
    }
    if (i < n) starts[i] = boff[blockIdx.x] + s[t] - v;
}

// ---------------- casts ----------------
__global__ void k_cast_x(const float* __restrict__ x, unsigned short* __restrict__ xb, int n4) {
    int i = blockIdx.x * blockDim.x + threadIdx.x;
    if (i >= n4) return;
    float4 v = *(const float4*)(x + (size_t)i * 4);
    ushort4 o;
    o.x = f2bf(v.x); o.y = f2bf(v.y); o.z = f2bf(v.z); o.w = f2bf(v.w);
    *(ushort4*)(xb + (size_t)i * 4) = o;
}

// Wcat = [Wl | Wr] rows [128 x 256], split into bf16 hi + lo.
__global__ void k_cast_w(const float* __restrict__ Wl, const float* __restrict__ Wr,
                         unsigned short* __restrict__ Whi, unsigned short* __restrict__ Wlo) {
    int row = blockIdx.x;    // 128
    int col = threadIdx.x;   // 256
    float w = (col < 128) ? Wl[row * 128 + col] : Wr[row * 128 + col - 128];
    unsigned short hi = f2bf(w);
    float lo = w - bf2f(hi);
    Whi[row * 256 + col] = hi;
    Wlo[row * 256 + col] = f2bf(lo);
}

// ---------------- fused SAGE layer: gather-agg + dual GEMM -----------------
// Block = 64 nodes x 128 j. Phase A: wave wv gather-aggregates nodes
// [wv*16, wv*16+16) into sA cols 0..127 (4-deep pipelined row loads).
// Phase B: stage h rows into sA cols 128..255. Barrier. MFMA K=256 against
// [Wl|Wr] hi+lo split; wave owns j-strip [32wv, 32wv+32).
__global__ __launch_bounds__(256) void k_layer(
    const unsigned short* __restrict__ hb, const int* __restrict__ starts,
    const int* __restrict__ csr,
    const unsigned short* __restrict__ Whi, const unsigned short* __restrict__ Wlo,
    const float* __restrict__ bl, unsigned short* __restrict__ outb, int n, int do_relu)
{
    __shared__ unsigned short sA[64 * 264];  // 33792 B
    int node0 = blockIdx.x * 64;
    int t = threadIdx.x;
    int wv = t >> 6;
    int lane = t & 63;

    // Phase A: gather-aggregate, 16 nodes per wave.
    const unsigned short* hlane = hb + lane * 2;
    for (int i = 0; i < 16; ++i) {
        int nd = wv * 16 + i;
        int node = node0 + nd;
        float ax = 0.f, ay = 0.f;
        if (node < n) {
            int s = starts[node], e = starts[node + 1];
            for (int base = s; base < e; base += 64) {
                int cntv = min(64, e - base);
                int idx = (base + lane < e) ? csr[base + lane] : 0;
                int j = 0;
                for (; j + 4 <= cntv; j += 4) {
                    int s0 = __shfl(idx, j + 0);
                    int s1 = __shfl(idx, j + 1);
                    int s2 = __shfl(idx, j + 2);
                    int s3 = __shfl(idx, j + 3);
                    unsigned v0 = *(const unsigned*)(hlane + (size_t)s0 * 128);
                    unsigned v1 = *(const unsigned*)(hlane + (size_t)s1 * 128);
                    unsigned v2 = *(const unsigned*)(hlane + (size_t)s2 * 128);
                    unsigned v3 = *(const unsigned*)(hlane + (size_t)s3 * 128);
                    ax += __builtin_bit_cast(float, v0 << 16);
                    ay += __builtin_bit_cast(float, v0 & 0xffff0000u);
                    ax += __builtin_bit_cast(float, v1 << 16);
                    ay += __builtin_bit_cast(float, v1 & 0xffff0000u);
                    ax += __builtin_bit_cast(float, v2 << 16);
                    ay += __builtin_bit_cast(float, v2 & 0xffff0000u);
                    ax += __builtin_bit_cast(float, v3 << 16);
                    ay += __builtin_bit_cast(float, v3 & 0xffff0000u);
                }
                for (; j < cntv; ++j) {
                    int s0 = __shfl(idx, j);
                    unsigned v0 = *(const unsigned*)(hlane + (size_t)s0 * 128);
                    ax += __builtin_bit_cast(float, v0 << 16);
                    ay += __builtin_bit_cast(float, v0 & 0xffff0000u);
                }
            }
        }
        unsigned o = (unsigned)f2bf(ax) | ((unsigned)f2bf(ay) << 16);
        *(unsigned*)(sA + nd * 264 + lane * 2) = o;
    }

    // Phase B: stage h rows (cols 128..255), coalesced uint4.
    for (int q = t; q < 1024; q += 256) {
        int nd = q >> 4;
        int c = q & 15;
        int node = node0 + nd;
        uint4 v = make_uint4(0u, 0u, 0u, 0u);
        if (node < n) v = *(const uint4*)(hb + (size_t)node * 128 + c * 8);
        *(uint4*)(sA + nd * 264 + 128 + c * 8) = v;
    }
    __syncthreads();

    // MFMA phase: wave wv owns j-strip [32wv, 32wv+32).
    int quad = lane >> 4;
    int mr = lane & 15;
    int jbase = wv * 32;

    f32x4 acc[4][2];
#pragma unroll
    for (int mi = 0; mi < 4; ++mi)
#pragma unroll
        for (int jj = 0; jj < 2; ++jj) acc[mi][jj] = (f32x4){0.f, 0.f, 0.f, 0.f};

    for (int s = 0; s < 8; ++s) {
        int koff = s * 32 + quad * 8;
        bf16x8 bh[2], bo[2];
#pragma unroll
        for (int jj = 0; jj < 2; ++jj) {
            size_t wo = (size_t)(jbase + jj * 16 + mr) * 256 + koff;
            bh[jj] = __builtin_bit_cast(bf16x8, *(const uint4*)(Whi + wo));
            bo[jj] = __builtin_bit_cast(bf16x8, *(const uint4*)(Wlo + wo));
        }
#pragma unroll
        for (int mi = 0; mi < 4; ++mi) {
            bf16x8 a = __builtin_bit_cast(
                bf16x8, *(const uint4*)(sA + (mi * 16 + mr) * 264 + koff));
#pragma unroll
            for (int jj = 0; jj < 2; ++jj) {
                acc[mi][jj] = __builtin_amdgcn_mfma_f32_16x16x32_bf16(a, bh[jj], acc[mi][jj], 0, 0, 0);
                acc[mi][jj] = __builtin_amdgcn_mfma_f32_16x16x32_bf16(a, bo[jj], acc[mi][jj], 0, 0, 0);
            }
        }
    }

    // Epilogue: C/D layout col=lane&15, row=quad*4+reg.
#pragma unroll
    for (int mi = 0; mi < 4; ++mi) {
#pragma unroll
        for (int jj = 0; jj < 2; ++jj) {
            int col = jbase + jj * 16 + mr;
            float bias = bl[col];
#pragma unroll
            for (int r = 0; r < 4; ++r) {
                int node = node0 + mi * 16 + quad * 4 + r;
                if (node >= n) continue;
                float v = acc[mi][jj][r] + bias;
                if (do_relu) v = fmaxf(v, 0.f);
                outb[(size_t)node * 128 + col] = f2bf(v);
            }
        }
    }
}

// ---------------- pool: one wave per 16-row strip, run-length flush --------
#define POOL_ROWS 16
__global__ __launch_bounds__(256) void k_pool(
    const unsigned short* __restrict__ hb, const int* __restrict__ batch,
    float* __restrict__ gsum, float* __restrict__ gcnt, int n)
{
    int wave = (blockIdx.x * 256 + threadIdx.x) >> 6;
    int lane = threadIdx.x & 63;
    int r0 = wave * POOL_ROWS;
    if (r0 >= n) return;
    int r1 = min(r0 + POOL_ROWS, n);
    int cur = batch[r0];
    float ax = 0.f, ay = 0.f, cnt = 0.f;
    for (int i = r0; i < r1; ++i) {
        int g = batch[i];
        unsigned v = *(const unsigned*)(hb + (size_t)i * 128 + lane * 2);
        if (g != cur) {
            atomicAdd(&gsum[cur * 128 + lane * 2], ax);
            atomicAdd(&gsum[cur * 128 + lane * 2 + 1], ay);
            if (lane == 0) atomicAdd(&gcnt[cur], cnt);
            ax = 0.f; ay = 0.f; cnt = 0.f; cur = g;
        }
        ax += __builtin_bit_cast(float, v << 16);
        ay += __builtin_bit_cast(float, v & 0xffff0000u);
        cnt += 1.f;
    }
    atomicAdd(&gsum[cur * 128 + lane * 2], ax);
    atomicAdd(&gsum[cur * 128 + lane * 2 + 1], ay);
    if (lane == 0) atomicAdd(&gcnt[cur], cnt);
}

__global__ void k_final(const float* __restrict__ gsum, const float* __restrict__ gcnt,
                        const float* __restrict__ Wlin, const float* __restrict__ blin,
                        float* __restrict__ out)
{
    int g = blockIdx.x;   // 64
    int o = threadIdx.x;  // 64
    float inv = 1.f / fmaxf(gcnt[g], 1.f);
    float acc = 0.f;
    for (int k = 0; k < 128; ++k)
        acc += gsum[g * 128 + k] * Wlin[o * 128 + k];
    out[g * 64 + o] = acc * inv + blin[o];
}

extern "C" void kernel_launch(void* const* d_in, const int* in_sizes, int n_in,
                              void* d_out, int out_size, void* d_ws, size_t ws_size,
                              hipStream_t stream) {
    const float* x     = (const float*)d_in[0];
    const int*   ei    = (const int*)d_in[1];
    const int*   batch = (const int*)d_in[2];
    const float* W1l = (const float*)d_in[3];
    const float* b1l = (const float*)d_in[4];
    const float* W1r = (const float*)d_in[5];
    const float* W2l = (const float*)d_in[6];
    const float* b2l = (const float*)d_in[7];
    const float* W2r = (const float*)d_in[8];
    const float* W3l = (const float*)d_in[9];
    const float* b3l = (const float*)d_in[10];
    const float* W3r = (const float*)d_in[11];
    const float* Wlin = (const float*)d_in[12];
    const float* blin = (const float*)d_in[13];

    const int N = in_sizes[2];       // 50000
    const int E = in_sizes[1] / 2;   // 800000
    const int nb = (N + 127) >> 7;   // 391 buckets
    const int epb = (E + BINB - 1) / BINB;  // 5000 edges per bin block

    size_t off = 0;
    auto alloc = [&](size_t bytes) {
        void* p = (char*)d_ws + off;
        off += (bytes + 255) & ~(size_t)255;
        return p;
    };
    int* csr_start = (int*)alloc((size_t)(N + 1) * 4);
    int* cnt       = (int*)alloc((size_t)N * 4);
    int* cnt_mat   = (int*)alloc((size_t)nb * BINB * 4);
    int* off_mat   = (int*)alloc((size_t)nb * BINB * 4);
    int* bsum      = (int*)alloc(256 * 4);
    int* boff      = (int*)alloc(256 * 4);
    int* bsum2     = (int*)alloc(256 * 4);
    int* boff2     = (int*)alloc(256 * 4);
    int* tot_scratch = (int*)alloc(256);
    int* csr_src   = (int*)alloc((size_t)E * 4);
    unsigned short* x_bf   = (unsigned short*)alloc((size_t)N * 128 * 2);
    unsigned short* hA     = (unsigned short*)alloc((size_t)N * 128 * 2);
    unsigned short* hB     = (unsigned short*)alloc((size_t)N * 128 * 2);
    unsigned short* scratch_bf = (unsigned short*)alloc((size_t)N * 128 * 2);
    unsigned short* W1hi = (unsigned short*)alloc(128 * 256 * 2);
    unsigned short* W1lo = (unsigned short*)alloc(128 * 256 * 2);
    unsigned short* W2hi = (unsigned short*)alloc(128 * 256 * 2);
    unsigned short* W2lo = (unsigned short*)alloc(128 * 256 * 2);
    unsigned short* W3hi = (unsigned short*)alloc(128 * 256 * 2);
    unsigned short* W3lo = (unsigned short*)alloc(128 * 256 * 2);
    float* gsum = (float*)alloc((size_t)64 * 128 * 4);
    float* gcnt = (float*)alloc((size_t)64 * 4);
    (void)ws_size;

    // binned aliases scratch_bf: E*4 <= N*256 bytes.
    unsigned* binned = (unsigned*)scratch_bf;

    hipMemsetAsync(gsum, 0, (size_t)64 * 128 * 4, stream);
    hipMemsetAsync(gcnt, 0, (size_t)64 * 4, stream);

    // --- CSR build via bucket counting sort ---
    int nmat = nb * BINB;                  // 62560
    int nscan_m = (nmat + 255) / 256;      // 245
    int nscan_n = (N + 255) / 256;         // 196

    k_bincount<<<BINB, 256, 0, stream>>>(ei + E, cnt_mat, E, nb, epb);
    k_scan1<<<nscan_m, 256, 0, stream>>>(cnt_mat, bsum2, nmat);
    k_scan2<<<1, 256, 0, stream>>>(bsum2, boff2, nscan_m, tot_scratch);
    k_scan3m<<<nscan_m, 256, 0, stream>>>(cnt_mat, boff2, off_mat, nmat);
    k_binscatter<<<BINB, 256, 0, stream>>>(ei, off_mat, binned, E, nb, epb);
    k_hist2<<<nb, 256, 0, stream>>>(binned, off_mat, cnt, E, nb, N);
    k_scan1<<<nscan_n, 256, 0, stream>>>(cnt, bsum, N);
    k_scan2<<<1, 256, 0, stream>>>(bsum, boff, nscan_n, csr_start + N);
    k_scan3m<<<nscan_n, 256, 0, stream>>>(cnt, boff, csr_start, N);
    k_fillfine<<<nb, 256, 0, stream>>>(binned, off_mat, csr_start, csr_src, E, nb, N);

    // Casts
    int n4 = N * 128 / 4;
    k_cast_x<<<(n4 + 255) / 256, 256, 0, stream>>>(x, x_bf, n4);
    k_cast_w<<<128, 256, 0, stream>>>(W1l, W1r, W1hi, W1lo);
    k_cast_w<<<128, 256, 0, stream>>>(W2l, W2r, W2hi, W2lo);
    k_cast_w<<<128, 256, 0, stream>>>(W3l, W3r, W3hi, W3lo);

    int layer_grid = (N + 63) / 64;

    // Fused layers
    k_layer<<<layer_grid, 256, 0, stream>>>(x_bf, csr_start, csr_src, W1hi, W1lo, b1l, hA, N, 1);
    k_layer<<<layer_grid, 256, 0, stream>>>(hA, csr_start, csr_src, W2hi, W2lo, b2l, hB, N, 1);
    k_layer<<<layer_grid, 256, 0, stream>>>(hB, csr_start, csr_src, W3hi, W3lo, b3l, hA, N, 0);

    // Pool + head
    int pool_waves = (N + POOL_ROWS - 1) / POOL_ROWS;
    int pool_blocks = (pool_waves + 3) / 4;
    k_pool<<<pool_blocks, 256, 0, stream>>>(hA, batch, gsum, gcnt, N);
    k_final<<<64, 64, 0, stream>>>(gsum, gcnt, Wlin, blin, (float*)d_out);
}

// Round 8
// 331.195 us; speedup vs baseline: 1.1314x; 1.1314x over previous
//
#include <hip/hip_runtime.h>

// HierarchicalGraphSAGE bf16-MFMA version, R8.
// N=50000, E=800000, D=128, OUT=64, G=64.
//
//  R8 changes vs R7:
//   - REVERTED the agg+sage fusion (R7 regression: fused kernel capped gather
//     occupancy at 29% via 33KB LDS + in-block barrier). Back to split
//     k_agg / k_sage (R6 structure).
//   - k_agg rewritten: lane = (edge-group 0..3, feature-block 0..15), each
//     lane loads uint4 -> one wave load fetches 4 full edge rows (1KB).
//     VMEM instrs/edge 1 -> 0.25, shfl/edge 1 -> 0.25. Cross-group
//     shfl_xor(16/32) reduction per node.
//   - kept R7's 4B packed binned[] (src|dst7<<16) in the CSR counting sort.

typedef __bf16 bf16x8 __attribute__((ext_vector_type(8)));
typedef float f32x4 __attribute__((ext_vector_type(4)));

#define BINB 160          // binning blocks
#define NBMAX 512         // max buckets (N <= 65536)

static __device__ __forceinline__ float bf2f(unsigned short u) {
    union { unsigned u; float f; } c; c.u = (unsigned)u << 16; return c.f;
}
static __device__ __forceinline__ unsigned short f2bf(float f) {
    unsigned u = __builtin_bit_cast(unsigned, f);
    return (unsigned short)((u + 0x7fffu + ((u >> 16) & 1u)) >> 16);
}

// ---------------- bucket counting sort ----------------
__global__ __launch_bounds__(256) void k_bincount(
    const int* __restrict__ dst, int* __restrict__ cnt_mat, int E, int nb, int epb)
{
    __shared__ int lc[NBMAX];
    for (int i = threadIdx.x; i < nb; i += 256) lc[i] = 0;
    __syncthreads();
    int b0 = blockIdx.x * epb;
    int b1 = min(b0 + epb, E);
    for (int i = b0 + threadIdx.x; i < b1; i += 256)
        atomicAdd(&lc[dst[i] >> 7], 1);
    __syncthreads();
    for (int i = threadIdx.x; i < nb; i += 256)
        cnt_mat[i * BINB + blockIdx.x] = lc[i];
}

__global__ __launch_bounds__(256) void k_binscatter(
    const int* __restrict__ ei, const int* __restrict__ off_mat,
    unsigned* __restrict__ binned, int E, int nb, int epb)
{
    __shared__ int lofs[NBMAX];
    __shared__ int lcnt[NBMAX];
    for (int i = threadIdx.x; i < nb; i += 256) {
        lofs[i] = off_mat[i * BINB + blockIdx.x];
        lcnt[i] = 0;
    }
    __syncthreads();
    int b0 = blockIdx.x * epb;
    int b1 = min(b0 + epb, E);
    for (int i = b0 + threadIdx.x; i < b1; i += 256) {
        int s = ei[i];
        int d = ei[E + i];
        int b = d >> 7;
        int r = atomicAdd(&lcnt[b], 1);
        binned[lofs[b] + r] = (unsigned)s | ((unsigned)(d & 127) << 16);
    }
}

// Per-node counts from the bucket's contiguous binned range (LDS atomics).
__global__ __launch_bounds__(256) void k_hist2(
    const unsigned* __restrict__ binned, const int* __restrict__ off_mat,
    int* __restrict__ counts, int E, int nb, int n)
{
    __shared__ int lc[128];
    int b = blockIdx.x;
    if (threadIdx.x < 128) lc[threadIdx.x] = 0;
    __syncthreads();
    int bs = off_mat[b * BINB];
    int be = (b == nb - 1) ? E : off_mat[(b + 1) * BINB];
    for (int i = bs + threadIdx.x; i < be; i += 256)
        atomicAdd(&lc[(binned[i] >> 16) & 127], 1);
    __syncthreads();
    int node = (b << 7) + threadIdx.x;
    if (threadIdx.x < 128 && node < n) counts[node] = lc[threadIdx.x];
}

// Fine scatter: slot counters in LDS, csr writes confined to bucket range.
__global__ __launch_bounds__(256) void k_fillfine(
    const unsigned* __restrict__ binned, const int* __restrict__ off_mat,
    const int* __restrict__ starts, int* __restrict__ csr_src, int E, int nb, int n)
{
    __shared__ int lpos[128];
    int b = blockIdx.x;
    int node0 = b << 7;
    if (threadIdx.x < 128) {
        int node = node0 + threadIdx.x;
        lpos[threadIdx.x] = (node < n) ? starts[node] : 0;
    }
    __syncthreads();
    int bs = off_mat[b * BINB];
    int be = (b == nb - 1) ? E : off_mat[(b + 1) * BINB];
    for (int i = bs + threadIdx.x; i < be; i += 256) {
        unsigned e = binned[i];
        int slot = atomicAdd(&lpos[(e >> 16) & 127], 1);
        csr_src[slot] = (int)(e & 0xffffu);
    }
}

// ---------------- hierarchical scan ----------------
__global__ __launch_bounds__(256) void k_scan1(
    const int* __restrict__ counts, int* __restrict__ bsum, int n)
{
    __shared__ int s[4];
    int i = blockIdx.x * 256 + threadIdx.x;
    int v = (i < n) ? counts[i] : 0;
#pragma unroll
    for (int off = 1; off < 64; off <<= 1) v += __shfl_xor(v, off);
    if ((threadIdx.x & 63) == 0) s[threadIdx.x >> 6] = v;
    __syncthreads();
    if (threadIdx.x == 0) bsum[blockIdx.x] = s[0] + s[1] + s[2] + s[3];
}

__global__ __launch_bounds__(256) void k_scan2(
    const int* __restrict__ bsum, int* __restrict__ boff, int nb, int* __restrict__ total_out)
{
    __shared__ int s[256];
    int t = threadIdx.x;
    int v = (t < nb) ? bsum[t] : 0;
    s[t] = v;
    __syncthreads();
#pragma unroll
    for (int off = 1; off < 256; off <<= 1) {
        int u = (t >= off) ? s[t - off] : 0;
        __syncthreads();
        s[t] += u;
        __syncthreads();
    }
    if (t < nb) boff[t] = s[t] - v;
    if (t == nb - 1) *total_out = s[t];
}

__global__ __launch_bounds__(256) void k_scan3m(
    const int* __restrict__ counts, const int* __restrict__ boff,
    int* __restrict__ starts, int n)
{
    __shared__ int s[256];
    int t = threadIdx.x;
    int i = blockIdx.x * 256 + t;
    int v = (i < n) ? counts[i] : 0;
    s[t] = v;
    __syncthreads();
#pragma unroll
    for (int off = 1; off < 256; off <<= 1) {
        int u = (t >= off) ? s[t - off] : 0;
        __syncthreads();
        s[t] += u;
        __syncthreads();
    }
    if (i < n) starts[i] = boff[blockIdx.x] + s[t] - v;
}

// ---------------- casts ----------------
__global__ void k_cast_x(const float* __restrict__ x, unsigned short* __restrict__ xb, int n4) {
    int i = blockIdx.x * blockDim.x + threadIdx.x;
    if (i >= n4) return;
    float4 v = *(const float4*)(x + (size_t)i * 4);
    ushort4 o;
    o.x = f2bf(v.x); o.y = f2bf(v.y); o.z = f2bf(v.z); o.w = f2bf(v.w);
    *(ushort4*)(xb + (size_t)i * 4) = o;
}

// Wcat = [Wl | Wr] rows [128 x 256], split into bf16 hi + lo.
__global__ void k_cast_w(const float* __restrict__ Wl, const float* __restrict__ Wr,
                         unsigned short* __restrict__ Whi, unsigned short* __restrict__ Wlo) {
    int row = blockIdx.x;    // 128
    int col = threadIdx.x;   // 256
    float w = (col < 128) ? Wl[row * 128 + col] : Wr[row * 128 + col - 128];
    unsigned short hi = f2bf(w);
    float lo = w - bf2f(hi);
    Whi[row * 256 + col] = hi;
    Wlo[row * 256 + col] = f2bf(lo);
}

// ---------------- aggregate: wave/node, 4 edge rows per wave load ----------
// lane = (eg 0..3, fb 0..15); lane loads uint4 = 16B of row -> one wave load
// covers 4 edges' full 256B rows. Cross-group shfl_xor(16/32) reduce at end.
__global__ __launch_bounds__(256) void k_agg(
    const unsigned short* __restrict__ hb, const int* __restrict__ starts,
    const int* __restrict__ csr, unsigned short* __restrict__ aggb, int n)
{
    int node = blockIdx.x * 4 + (threadIdx.x >> 6);
    int lane = threadIdx.x & 63;
    if (node >= n) return;
    int eg = lane >> 4;   // edge group within 4-edge step
    int fb = lane & 15;   // feature block: ushorts [fb*8, fb*8+8)
    const unsigned short* hrow = hb + fb * 8;
    int s = starts[node], e = starts[node + 1];
    float a0 = 0.f, a1 = 0.f, a2 = 0.f, a3 = 0.f,
          a4 = 0.f, a5 = 0.f, a6 = 0.f, a7 = 0.f;

#define ACC8(v)                                                 \
    do {                                                        \
        a0 += __builtin_bit_cast(float, (v).x << 16);           \
        a1 += __builtin_bit_cast(float, (v).x & 0xffff0000u);   \
        a2 += __builtin_bit_cast(float, (v).y << 16);           \
        a3 += __builtin_bit_cast(float, (v).y & 0xffff0000u);   \
        a4 += __builtin_bit_cast(float, (v).z << 16);           \
        a5 += __builtin_bit_cast(float, (v).z & 0xffff0000u);   \
        a6 += __builtin_bit_cast(float, (v).w << 16);           \
        a7 += __builtin_bit_cast(float, (v).w & 0xffff0000u);   \
    } while (0)

    for (int base = s; base < e; base += 64) {
        int cnt = min(64, e - base);
        int idx = (base + lane < e) ? csr[base + lane] : 0;
        int j = 0;
        for (; j + 8 <= cnt; j += 8) {   // 8 edges, 2 fat loads in flight
            int s0 = __shfl(idx, j + eg);
            int s1 = __shfl(idx, j + 4 + eg);
            uint4 v0 = *(const uint4*)(hrow + (size_t)s0 * 128);
            uint4 v1 = *(const uint4*)(hrow + (size_t)s1 * 128);
            ACC8(v0);
            ACC8(v1);
        }
        for (; j + 4 <= cnt; j += 4) {   // one unmasked 4-edge step
            int s0 = __shfl(idx, j + eg);
            uint4 v0 = *(const uint4*)(hrow + (size_t)s0 * 128);
            ACC8(v0);
        }
        if (j < cnt) {                   // masked tail step
            int k = j + eg;
            int sm = __shfl(idx, (k < cnt) ? k : (cnt - 1));
            uint4 v = *(const uint4*)(hrow + (size_t)sm * 128);
            if (k >= cnt) v = make_uint4(0u, 0u, 0u, 0u);
            ACC8(v);
        }
    }
#undef ACC8

    // Reduce across the 4 edge groups (lanes l, l^16, l^32 hold same fb).
    a0 += __shfl_xor(a0, 16); a0 += __shfl_xor(a0, 32);
    a1 += __shfl_xor(a1, 16); a1 += __shfl_xor(a1, 32);
    a2 += __shfl_xor(a2, 16); a2 += __shfl_xor(a2, 32);
    a3 += __shfl_xor(a3, 16); a3 += __shfl_xor(a3, 32);
    a4 += __shfl_xor(a4, 16); a4 += __shfl_xor(a4, 32);
    a5 += __shfl_xor(a5, 16); a5 += __shfl_xor(a5, 32);
    a6 += __shfl_xor(a6, 16); a6 += __shfl_xor(a6, 32);
    a7 += __shfl_xor(a7, 16); a7 += __shfl_xor(a7, 32);

    unsigned u0 = (unsigned)f2bf(a0) | ((unsigned)f2bf(a1) << 16);
    unsigned u1 = (unsigned)f2bf(a2) | ((unsigned)f2bf(a3) << 16);
    unsigned u2 = (unsigned)f2bf(a4) | ((unsigned)f2bf(a5) << 16);
    unsigned u3 = (unsigned)f2bf(a6) | ((unsigned)f2bf(a7) << 16);
    if (eg == 0)
        *(uint4*)(aggb + (size_t)node * 128 + fb * 8) = make_uint4(u0, u1, u2, u3);
}

// ---------------- SAGE layer GEMM via bf16 MFMA ----------------
// C[m][j] = relu?( bl[j] + sum_k A[m][k]*W[j][k] ), A=[agg|h] (K=256).
// Block 256 thr = 4 waves, tile 64 m x 128 j. Wave w owns j-strip
// [32w, 32w+32): B frags (hi/lo x 2 jj) stay in VGPRs across 4 m-subtiles.
__global__ __launch_bounds__(256) void k_sage(
    const unsigned short* __restrict__ aggb, const unsigned short* __restrict__ hb,
    const unsigned short* __restrict__ Whi, const unsigned short* __restrict__ Wlo,
    const float* __restrict__ bl, unsigned short* __restrict__ outb, int n, int do_relu)
{
    __shared__ unsigned short sA[64 * 264];  // 33792 B
    int node0 = blockIdx.x * 64;
    int t = threadIdx.x;

    for (int q = t; q < 2048; q += 256) {
        int nd = q >> 5;
        int c = q & 31;
        int node = node0 + nd;
        uint4 v = make_uint4(0u, 0u, 0u, 0u);
        if (node < n) {
            const unsigned short* src = (c < 16)
                ? (aggb + (size_t)node * 128 + c * 8)
                : (hb + (size_t)node * 128 + (c - 16) * 8);
            v = *(const uint4*)src;
        }
        *(uint4*)(sA + nd * 264 + c * 8) = v;
    }
    __syncthreads();

    int wv = t >> 6;
    int l = t & 63;
    int quad = l >> 4;
    int mr = l & 15;
    int jbase = wv * 32;

    f32x4 acc[4][2];
#pragma unroll
    for (int mi = 0; mi < 4; ++mi)
#pragma unroll
        for (int jj = 0; jj < 2; ++jj) acc[mi][jj] = (f32x4){0.f, 0.f, 0.f, 0.f};

    for (int s = 0; s < 8; ++s) {
        int koff = s * 32 + quad * 8;
        bf16x8 bh[2], bo[2];
#pragma unroll
        for (int jj = 0; jj < 2; ++jj) {
            size_t wo = (size_t)(jbase + jj * 16 + mr) * 256 + koff;
            bh[jj] = __builtin_bit_cast(bf16x8, *(const uint4*)(Whi + wo));
            bo[jj] = __builtin_bit_cast(bf16x8, *(const uint4*)(Wlo + wo));
        }
#pragma unroll
        for (int mi = 0; mi < 4; ++mi) {
            bf16x8 a = __builtin_bit_cast(
                bf16x8, *(const uint4*)(sA + (mi * 16 + mr) * 264 + koff));
#pragma unroll
            for (int jj = 0; jj < 2; ++jj) {
                acc[mi][jj] = __builtin_amdgcn_mfma_f32_16x16x32_bf16(a, bh[jj], acc[mi][jj], 0, 0, 0);
                acc[mi][jj] = __builtin_amdgcn_mfma_f32_16x16x32_bf16(a, bo[jj], acc[mi][jj], 0, 0, 0);
            }
        }
    }

#pragma unroll
    for (int mi = 0; mi < 4; ++mi) {
#pragma unroll
        for (int jj = 0; jj < 2; ++jj) {
            int col = jbase + jj * 16 + mr;
            float bias = bl[col];
#pragma unroll
            for (int r = 0; r < 4; ++r) {
                int node = node0 + mi * 16 + quad * 4 + r;
                if (node >= n) continue;
                float v = acc[mi][jj][r] + bias;
                if (do_relu) v = fmaxf(v, 0.f);
                outb[(size_t)node * 128 + col] = f2bf(v);
            }
        }
    }
}

// ---------------- pool: one wave per 16-row strip, run-length flush --------
#define POOL_ROWS 16
__global__ __launch_bounds__(256) void k_pool(
    const unsigned short* __restrict__ hb, const int* __restrict__ batch,
    float* __restrict__ gsum, float* __restrict__ gcnt, int n)
{
    int wave = (blockIdx.x * 256 + threadIdx.x) >> 6;
    int lane = threadIdx.x & 63;
    int r0 = wave * POOL_ROWS;
    if (r0 >= n) return;
    int r1 = min(r0 + POOL_ROWS, n);
    int cur = batch[r0];
    float ax = 0.f, ay = 0.f, cnt = 0.f;
    for (int i = r0; i < r1; ++i) {
        int g = batch[i];
        unsigned v = *(const unsigned*)(hb + (size_t)i * 128 + lane * 2);
        if (g != cur) {
            atomicAdd(&gsum[cur * 128 + lane * 2], ax);
            atomicAdd(&gsum[cur * 128 + lane * 2 + 1], ay);
            if (lane == 0) atomicAdd(&gcnt[cur], cnt);
            ax = 0.f; ay = 0.f; cnt = 0.f; cur = g;
        }
        ax += __builtin_bit_cast(float, v << 16);
        ay += __builtin_bit_cast(float, v & 0xffff0000u);
        cnt += 1.f;
    }
    atomicAdd(&gsum[cur * 128 + lane * 2], ax);
    atomicAdd(&gsum[cur * 128 + lane * 2 + 1], ay);
    if (lane == 0) atomicAdd(&gcnt[cur], cnt);
}

__global__ void k_final(const float* __restrict__ gsum, const float* __restrict__ gcnt,
                        const float* __restrict__ Wlin, const float* __restrict__ blin,
                        float* __restrict__ out)
{
    int g = blockIdx.x;   // 64
    int o = threadIdx.x;  // 64
    float inv = 1.f / fmaxf(gcnt[g], 1.f);
    float acc = 0.f;
    for (int k = 0; k < 128; ++k)
        acc += gsum[g * 128 + k] * Wlin[o * 128 + k];
    out[g * 64 + o] = acc * inv + blin[o];
}

extern "C" void kernel_launch(void* const* d_in, const int* in_sizes, int n_in,
                              void* d_out, int out_size, void* d_ws, size_t ws_size,
                              hipStream_t stream) {
    const float* x     = (const float*)d_in[0];
    const int*   ei    = (const int*)d_in[1];
    const int*   batch = (const int*)d_in[2];
    const float* W1l = (const float*)d_in[3];
    const float* b1l = (const float*)d_in[4];
    const float* W1r = (const float*)d_in[5];
    const float* W2l = (const float*)d_in[6];
    const float* b2l = (const float*)d_in[7];
    const float* W2r = (const float*)d_in[8];
    const float* W3l = (const float*)d_in[9];
    const float* b3l = (const float*)d_in[10];
    const float* W3r = (const float*)d_in[11];
    const float* Wlin = (const float*)d_in[12];
    const float* blin = (const float*)d_in[13];

    const int N = in_sizes[2];       // 50000
    const int E = in_sizes[1] / 2;   // 800000
    const int nb = (N + 127) >> 7;   // 391 buckets
    const int epb = (E + BINB - 1) / BINB;  // 5000 edges per bin block

    size_t off = 0;
    auto alloc = [&](size_t bytes) {
        void* p = (char*)d_ws + off;
        off += (bytes + 255) & ~(size_t)255;
        return p;
    };
    int* csr_start = (int*)alloc((size_t)(N + 1) * 4);
    int* cnt       = (int*)alloc((size_t)N * 4);
    int* cnt_mat   = (int*)alloc((size_t)nb * BINB * 4);
    int* off_mat   = (int*)alloc((size_t)nb * BINB * 4);
    int* bsum      = (int*)alloc(256 * 4);
    int* boff      = (int*)alloc(256 * 4);
    int* bsum2     = (int*)alloc(256 * 4);
    int* boff2     = (int*)alloc(256 * 4);
    int* tot_scratch = (int*)alloc(256);
    int* csr_src   = (int*)alloc((size_t)E * 4);
    unsigned short* x_bf   = (unsigned short*)alloc((size_t)N * 128 * 2);
    unsigned short* hA     = (unsigned short*)alloc((size_t)N * 128 * 2);
    unsigned short* hB     = (unsigned short*)alloc((size_t)N * 128 * 2);
    unsigned short* agg_bf = (unsigned short*)alloc((size_t)N * 128 * 2);
    unsigned short* W1hi = (unsigned short*)alloc(128 * 256 * 2);
    unsigned short* W1lo = (unsigned short*)alloc(128 * 256 * 2);
    unsigned short* W2hi = (unsigned short*)alloc(128 * 256 * 2);
    unsigned short* W2lo = (unsigned short*)alloc(128 * 256 * 2);
    unsigned short* W3hi = (unsigned short*)alloc(128 * 256 * 2);
    unsigned short* W3lo = (unsigned short*)alloc(128 * 256 * 2);
    float* gsum = (float*)alloc((size_t)64 * 128 * 4);
    float* gcnt = (float*)alloc((size_t)64 * 4);
    (void)ws_size;

    // binned aliases agg_bf: dead until first k_agg, E*4 <= N*256 bytes.
    unsigned* binned = (unsigned*)agg_bf;

    hipMemsetAsync(gsum, 0, (size_t)64 * 128 * 4, stream);
    hipMemsetAsync(gcnt, 0, (size_t)64 * 4, stream);

    // --- CSR build via bucket counting sort ---
    int nmat = nb * BINB;                  // 62560
    int nscan_m = (nmat + 255) / 256;      // 245
    int nscan_n = (N + 255) / 256;         // 196

    k_bincount<<<BINB, 256, 0, stream>>>(ei + E, cnt_mat, E, nb, epb);
    k_scan1<<<nscan_m, 256, 0, stream>>>(cnt_mat, bsum2, nmat);
    k_scan2<<<1, 256, 0, stream>>>(bsum2, boff2, nscan_m, tot_scratch);
    k_scan3m<<<nscan_m, 256, 0, stream>>>(cnt_mat, boff2, off_mat, nmat);
    k_binscatter<<<BINB, 256, 0, stream>>>(ei, off_mat, binned, E, nb, epb);
    k_hist2<<<nb, 256, 0, stream>>>(binned, off_mat, cnt, E, nb, N);
    k_scan1<<<nscan_n, 256, 0, stream>>>(cnt, bsum, N);
    k_scan2<<<1, 256, 0, stream>>>(bsum, boff, nscan_n, csr_start + N);
    k_scan3m<<<nscan_n, 256, 0, stream>>>(cnt, boff, csr_start, N);
    k_fillfine<<<nb, 256, 0, stream>>>(binned, off_mat, csr_start, csr_src, E, nb, N);

    // Casts
    int n4 = N * 128 / 4;
    k_cast_x<<<(n4 + 255) / 256, 256, 0, stream>>>(x, x_bf, n4);
    k_cast_w<<<128, 256, 0, stream>>>(W1l, W1r, W1hi, W1lo);
    k_cast_w<<<128, 256, 0, stream>>>(W2l, W2r, W2hi, W2lo);
    k_cast_w<<<128, 256, 0, stream>>>(W3l, W3r, W3hi, W3lo);

    int agg_grid = (N + 3) / 4;
    int sage_grid = (N + 63) / 64;

    // Layer 1: x_bf -> hA (relu)
    k_agg<<<agg_grid, 256, 0, stream>>>(x_bf, csr_start, csr_src, agg_bf, N);
    k_sage<<<sage_grid, 256, 0, stream>>>(agg_bf, x_bf, W1hi, W1lo, b1l, hA, N, 1);
    // Layer 2: hA -> hB (relu)
    k_agg<<<agg_grid, 256, 0, stream>>>(hA, csr_start, csr_src, agg_bf, N);
    k_sage<<<sage_grid, 256, 0, stream>>>(agg_bf, hA, W2hi, W2lo, b2l, hB, N, 1);
    // Layer 3: hB -> hA (no relu)
    k_agg<<<agg_grid, 256, 0, stream>>>(hB, csr_start, csr_src, agg_bf, N);
    k_sage<<<sage_grid, 256, 0, stream>>>(agg_bf, hB, W3hi, W3lo, b3l, hA, N, 0);

    // Pool + head
    int pool_waves = (N + POOL_ROWS - 1) / POOL_ROWS;
    int pool_blocks = (pool_waves + 3) / 4;
    k_pool<<<pool_blocks, 256, 0, stream>>>(hA, batch, gsum, gcnt, N);
    k_final<<<64, 64, 0, stream>>>(gsum, gcnt, Wlin, blin, (float*)d_out);
}

// Round 9
// 324.382 us; speedup vs baseline: 1.1552x; 1.0210x over previous
//
#include <hip/hip_runtime.h>

// HierarchicalGraphSAGE bf16-MFMA version, R9.
// N=50000, E=800000, D=128, OUT=64, G=64.
//
//  R9 changes vs R8:
//   - Gather operand stored in fp8 e4m3 (HW cvt_pk builtins): k_agg reads
//     128B rows instead of 256B -> halves the L2-miss-bound random traffic
//     (R8 showed gather is byte-bound, not issue-bound). Aggregate still
//     accumulated fp32, written bf16 -> k_sage numerics unchanged.
//   - csr_src is ushort (N < 65536): halves index reads + fine-scatter writes.
//   - 3x k_cast_w merged into one launch (contiguous Whi/Wlo per layer).

typedef __bf16 bf16x8 __attribute__((ext_vector_type(8)));
typedef float f32x4 __attribute__((ext_vector_type(4)));
typedef float f32x2 __attribute__((ext_vector_type(2)));

#define BINB 160          // binning blocks
#define NBMAX 512         // max buckets (N <= 65536)

static __device__ __forceinline__ float bf2f(unsigned short u) {
    union { unsigned u; float f; } c; c.u = (unsigned)u << 16; return c.f;
}
static __device__ __forceinline__ unsigned short f2bf(float f) {
    unsigned u = __builtin_bit_cast(unsigned, f);
    return (unsigned short)((u + 0x7fffu + ((u >> 16) & 1u)) >> 16);
}
// pack 8 floats -> 8 fp8 e4m3 (OCP) in a uint2
static __device__ __forceinline__ uint2 pk8_fp8(const float* f) {
    int lo = 0, hi = 0;
    lo = __builtin_amdgcn_cvt_pk_fp8_f32(f[0], f[1], lo, false);
    lo = __builtin_amdgcn_cvt_pk_fp8_f32(f[2], f[3], lo, true);
    hi = __builtin_amdgcn_cvt_pk_fp8_f32(f[4], f[5], hi, false);
    hi = __builtin_amdgcn_cvt_pk_fp8_f32(f[6], f[7], hi, true);
    return make_uint2((unsigned)lo, (unsigned)hi);
}

// ---------------- bucket counting sort ----------------
__global__ __launch_bounds__(256) void k_bincount(
    const int* __restrict__ dst, int* __restrict__ cnt_mat, int E, int nb, int epb)
{
    __shared__ int lc[NBMAX];
    for (int i = threadIdx.x; i < nb; i += 256) lc[i] = 0;
    __syncthreads();
    int b0 = blockIdx.x * epb;
    int b1 = min(b0 + epb, E);
    for (int i = b0 + threadIdx.x; i < b1; i += 256)
        atomicAdd(&lc[dst[i] >> 7], 1);
    __syncthreads();
    for (int i = threadIdx.x; i < nb; i += 256)
        cnt_mat[i * BINB + blockIdx.x] = lc[i];
}

__global__ __launch_bounds__(256) void k_binscatter(
    const int* __restrict__ ei, const int* __restrict__ off_mat,
    unsigned* __restrict__ binned, int E, int nb, int epb)
{
    __shared__ int lofs[NBMAX];
    __shared__ int lcnt[NBMAX];
    for (int i = threadIdx.x; i < nb; i += 256) {
        lofs[i] = off_mat[i * BINB + blockIdx.x];
        lcnt[i] = 0;
    }
    __syncthreads();
    int b0 = blockIdx.x * epb;
    int b1 = min(b0 + epb, E);
    for (int i = b0 + threadIdx.x; i < b1; i += 256) {
        int s = ei[i];
        int d = ei[E + i];
        int b = d >> 7;
        int r = atomicAdd(&lcnt[b], 1);
        binned[lofs[b] + r] = (unsigned)s | ((unsigned)(d & 127) << 16);
    }
}

// Per-node counts from the bucket's contiguous binned range (LDS atomics).
__global__ __launch_bounds__(256) void k_hist2(
    const unsigned* __restrict__ binned, const int* __restrict__ off_mat,
    int* __restrict__ counts, int E, int nb, int n)
{
    __shared__ int lc[128];
    int b = blockIdx.x;
    if (threadIdx.x < 128) lc[threadIdx.x] = 0;
    __syncthreads();
    int bs = off_mat[b * BINB];
    int be = (b == nb - 1) ? E : off_mat[(b + 1) * BINB];
    for (int i = bs + threadIdx.x; i < be; i += 256)
        atomicAdd(&lc[(binned[i] >> 16) & 127], 1);
    __syncthreads();
    int node = (b << 7) + threadIdx.x;
    if (threadIdx.x < 128 && node < n) counts[node] = lc[threadIdx.x];
}

// Fine scatter: slot counters in LDS, csr writes confined to bucket range.
__global__ __launch_bounds__(256) void k_fillfine(
    const unsigned* __restrict__ binned, const int* __restrict__ off_mat,
    const int* __restrict__ starts, unsigned short* __restrict__ csr_src,
    int E, int nb, int n)
{
    __shared__ int lpos[128];
    int b = blockIdx.x;
    int node0 = b << 7;
    if (threadIdx.x < 128) {
        int node = node0 + threadIdx.x;
        lpos[threadIdx.x] = (node < n) ? starts[node] : 0;
    }
    __syncthreads();
    int bs = off_mat[b * BINB];
    int be = (b == nb - 1) ? E : off_mat[(b + 1) * BINB];
    for (int i = bs + threadIdx.x; i < be; i += 256) {
        unsigned e = binned[i];
        int slot = atomicAdd(&lpos[(e >> 16) & 127], 1);
        csr_src[slot] = (unsigned short)(e & 0xffffu);
    }
}

// ---------------- hierarchical scan ----------------
__global__ __launch_bounds__(256) void k_scan1(
    const int* __restrict__ counts, int* __restrict__ bsum, int n)
{
    __shared__ int s[4];
    int i = blockIdx.x * 256 + threadIdx.x;
    int v = (i < n) ? counts[i] : 0;
#pragma unroll
    for (int off = 1; off < 64; off <<= 1) v += __shfl_xor(v, off);
    if ((threadIdx.x & 63) == 0) s[threadIdx.x >> 6] = v;
    __syncthreads();
    if (threadIdx.x == 0) bsum[blockIdx.x] = s[0] + s[1] + s[2] + s[3];
}

__global__ __launch_bounds__(256) void k_scan2(
    const int* __restrict__ bsum, int* __restrict__ boff, int nb, int* __restrict__ total_out)
{
    __shared__ int s[256];
    int t = threadIdx.x;
    int v = (t < nb) ? bsum[t] : 0;
    s[t] = v;
    __syncthreads();
#pragma unroll
    for (int off = 1; off < 256; off <<= 1) {
        int u = (t >= off) ? s[t - off] : 0;
        __syncthreads();
        s[t] += u;
        __syncthreads();
    }
    if (t < nb) boff[t] = s[t] - v;
    if (t == nb - 1) *total_out = s[t];
}

__global__ __launch_bounds__(256) void k_scan3m(
    const int* __restrict__ counts, const int* __restrict__ boff,
    int* __restrict__ starts, int n)
{
    __shared__ int s[256];
    int t = threadIdx.x;
    int i = blockIdx.x * 256 + t;
    int v = (i < n) ? counts[i] : 0;
    s[t] = v;
    __syncthreads();
#pragma unroll
    for (int off = 1; off < 256; off <<= 1) {
        int u = (t >= off) ? s[t - off] : 0;
        __syncthreads();
        s[t] += u;
        __syncthreads();
    }
    if (i < n) starts[i] = boff[blockIdx.x] + s[t] - v;
}

// ---------------- casts ----------------
// x -> bf16 + fp8, 8 elements per thread.
__global__ __launch_bounds__(256) void k_cast_x(
    const float* __restrict__ x, unsigned short* __restrict__ xb,
    unsigned char* __restrict__ x8, int n8)
{
    int i = blockIdx.x * blockDim.x + threadIdx.x;
    if (i >= n8) return;
    float f[8];
    *(float4*)(f + 0) = *(const float4*)(x + (size_t)i * 8);
    *(float4*)(f + 4) = *(const float4*)(x + (size_t)i * 8 + 4);
    ushort4 oa, ob;
    oa.x = f2bf(f[0]); oa.y = f2bf(f[1]); oa.z = f2bf(f[2]); oa.w = f2bf(f[3]);
    ob.x = f2bf(f[4]); ob.y = f2bf(f[5]); ob.z = f2bf(f[6]); ob.w = f2bf(f[7]);
    *(ushort4*)(xb + (size_t)i * 8) = oa;
    *(ushort4*)(xb + (size_t)i * 8 + 4) = ob;
    *(uint2*)(x8 + (size_t)i * 8) = pk8_fp8(f);
}

// bf16 h -> fp8 copy (for next layer's gather), 8 elements per thread.
__global__ __launch_bounds__(256) void k_cast8(
    const unsigned short* __restrict__ hb, unsigned char* __restrict__ h8, int n8)
{
    int i = blockIdx.x * blockDim.x + threadIdx.x;
    if (i >= n8) return;
    ushort4 a = *(const ushort4*)(hb + (size_t)i * 8);
    ushort4 b = *(const ushort4*)(hb + (size_t)i * 8 + 4);
    float f[8] = { bf2f(a.x), bf2f(a.y), bf2f(a.z), bf2f(a.w),
                   bf2f(b.x), bf2f(b.y), bf2f(b.z), bf2f(b.w) };
    *(uint2*)(h8 + (size_t)i * 8) = pk8_fp8(f);
}

// All 3 layers' Wcat = [Wl | Wr] -> bf16 hi + lo, contiguous per layer.
__global__ void k_cast_w(const float* __restrict__ W1l, const float* __restrict__ W1r,
                         const float* __restrict__ W2l, const float* __restrict__ W2r,
                         const float* __restrict__ W3l, const float* __restrict__ W3r,
                         unsigned short* __restrict__ Whi, unsigned short* __restrict__ Wlo) {
    int layer = blockIdx.x >> 7;   // 0..2
    int row = blockIdx.x & 127;    // 128
    int col = threadIdx.x;         // 256
    const float* Wl = (layer == 0) ? W1l : (layer == 1) ? W2l : W3l;
    const float* Wr = (layer == 0) ? W1r : (layer == 1) ? W2r : W3r;
    float w = (col < 128) ? Wl[row * 128 + col] : Wr[row * 128 + col - 128];
    unsigned short hi = f2bf(w);
    float lo = w - bf2f(hi);
    size_t o = (size_t)layer * 32768 + row * 256 + col;
    Whi[o] = hi;
    Wlo[o] = f2bf(lo);
}

// ---------------- aggregate: wave/node, fp8 rows, 4 edges per wave load ----
// lane = (eg 0..3, fb 0..15); lane loads uint2 = 8 fp8 -> one wave load
// covers 4 edges' full 128B rows. Cross-group shfl_xor(16/32) reduce at end.
__global__ __launch_bounds__(256) void k_agg(
    const unsigned char* __restrict__ h8, const int* __restrict__ starts,
    const unsigned short* __restrict__ csr, unsigned short* __restrict__ aggb, int n)
{
    int node = blockIdx.x * 4 + (threadIdx.x >> 6);
    int lane = threadIdx.x & 63;
    if (node >= n) return;
    int eg = lane >> 4;   // edge group within 4-edge step
    int fb = lane & 15;   // feature block: fp8s [fb*8, fb*8+8)
    const unsigned char* hrow = h8 + fb * 8;
    int s = starts[node], e = starts[node + 1];
    float a0 = 0.f, a1 = 0.f, a2 = 0.f, a3 = 0.f,
          a4 = 0.f, a5 = 0.f, a6 = 0.f, a7 = 0.f;

#define ACC8(v)                                                         \
    do {                                                                \
        f32x2 p0 = __builtin_amdgcn_cvt_pk_f32_fp8((v).x, false);       \
        f32x2 p1 = __builtin_amdgcn_cvt_pk_f32_fp8((v).x, true);        \
        f32x2 p2 = __builtin_amdgcn_cvt_pk_f32_fp8((v).y, false);       \
        f32x2 p3 = __builtin_amdgcn_cvt_pk_f32_fp8((v).y, true);        \
        a0 += p0.x; a1 += p0.y; a2 += p1.x; a3 += p1.y;                 \
        a4 += p2.x; a5 += p2.y; a6 += p3.x; a7 += p3.y;                 \
    } while (0)

    for (int base = s; base < e; base += 64) {
        int cnt = min(64, e - base);
        int idx = (base + lane < e) ? (int)csr[base + lane] : 0;
        int j = 0;
        for (; j + 8 <= cnt; j += 8) {   // 8 edges, 2 fat loads in flight
            int s0 = __shfl(idx, j + eg);
            int s1 = __shfl(idx, j + 4 + eg);
            uint2 v0 = *(const uint2*)(hrow + (size_t)s0 * 128);
            uint2 v1 = *(const uint2*)(hrow + (size_t)s1 * 128);
            ACC8(v0);
            ACC8(v1);
        }
        for (; j + 4 <= cnt; j += 4) {   // one unmasked 4-edge step
            int s0 = __shfl(idx, j + eg);
            uint2 v0 = *(const uint2*)(hrow + (size_t)s0 * 128);
            ACC8(v0);
        }
        if (j < cnt) {                   // masked tail step
            int k = j + eg;
            int sm = __shfl(idx, (k < cnt) ? k : (cnt - 1));
            uint2 v = *(const uint2*)(hrow + (size_t)sm * 128);
            if (k >= cnt) v = make_uint2(0u, 0u);
            ACC8(v);
        }
    }
#undef ACC8

    // Reduce across the 4 edge groups (lanes l, l^16, l^32 hold same fb).
    a0 += __shfl_xor(a0, 16); a0 += __shfl_xor(a0, 32);
    a1 += __shfl_xor(a1, 16); a1 += __shfl_xor(a1, 32);
    a2 += __shfl_xor(a2, 16); a2 += __shfl_xor(a2, 32);
    a3 += __shfl_xor(a3, 16); a3 += __shfl_xor(a3, 32);
    a4 += __shfl_xor(a4, 16); a4 += __shfl_xor(a4, 32);
    a5 += __shfl_xor(a5, 16); a5 += __shfl_xor(a5, 32);
    a6 += __shfl_xor(a6, 16); a6 += __shfl_xor(a6, 32);
    a7 += __shfl_xor(a7, 16); a7 += __shfl_xor(a7, 32);

    unsigned u0 = (unsigned)f2bf(a0) | ((unsigned)f2bf(a1) << 16);
    unsigned u1 = (unsigned)f2bf(a2) | ((unsigned)f2bf(a3) << 16);
    unsigned u2 = (unsigned)f2bf(a4) | ((unsigned)f2bf(a5) << 16);
    unsigned u3 = (unsigned)f2bf(a6) | ((unsigned)f2bf(a7) << 16);
    if (eg == 0)
        *(uint4*)(aggb + (size_t)node * 128 + fb * 8) = make_uint4(u0, u1, u2, u3);
}

// ---------------- SAGE layer GEMM via bf16 MFMA ----------------
// C[m][j] = relu?( bl[j] + sum_k A[m][k]*W[j][k] ), A=[agg|h] (K=256).
// Block 256 thr = 4 waves, tile 64 m x 128 j. Wave w owns j-strip
// [32w, 32w+32): B frags (hi/lo x 2 jj) stay in VGPRs across 4 m-subtiles.
__global__ __launch_bounds__(256) void k_sage(
    const unsigned short* __restrict__ aggb, const unsigned short* __restrict__ hb,
    const unsigned short* __restrict__ Whi, const unsigned short* __restrict__ Wlo,
    const float* __restrict__ bl, unsigned short* __restrict__ outb, int n, int do_relu)
{
    __shared__ unsigned short sA[64 * 264];  // 33792 B
    int node0 = blockIdx.x * 64;
    int t = threadIdx.x;

    for (int q = t; q < 2048; q += 256) {
        int nd = q >> 5;
        int c = q & 31;
        int node = node0 + nd;
        uint4 v = make_uint4(0u, 0u, 0u, 0u);
        if (node < n) {
            const unsigned short* src = (c < 16)
                ? (aggb + (size_t)node * 128 + c * 8)
                : (hb + (size_t)node * 128 + (c - 16) * 8);
            v = *(const uint4*)src;
        }
        *(uint4*)(sA + nd * 264 + c * 8) = v;
    }
    __syncthreads();

    int wv = t >> 6;
    int l = t & 63;
    int quad = l >> 4;
    int mr = l & 15;
    int jbase = wv * 32;

    f32x4 acc[4][2];
#pragma unroll
    for (int mi = 0; mi < 4; ++mi)
#pragma unroll
        for (int jj = 0; jj < 2; ++jj) acc[mi][jj] = (f32x4){0.f, 0.f, 0.f, 0.f};

    for (int s = 0; s < 8; ++s) {
        int koff = s * 32 + quad * 8;
        bf16x8 bh[2], bo[2];
#pragma unroll
        for (int jj = 0; jj < 2; ++jj) {
            size_t wo = (size_t)(jbase + jj * 16 + mr) * 256 + koff;
            bh[jj] = __builtin_bit_cast(bf16x8, *(const uint4*)(Whi + wo));
            bo[jj] = __builtin_bit_cast(bf16x8, *(const uint4*)(Wlo + wo));
        }
#pragma unroll
        for (int mi = 0; mi < 4; ++mi) {
            bf16x8 a = __builtin_bit_cast(
                bf16x8, *(const uint4*)(sA + (mi * 16 + mr) * 264 + koff));
#pragma unroll
            for (int jj = 0; jj < 2; ++jj) {
                acc[mi][jj] = __builtin_amdgcn_mfma_f32_16x16x32_bf16(a, bh[jj], acc[mi][jj], 0, 0, 0);
                acc[mi][jj] = __builtin_amdgcn_mfma_f32_16x16x32_bf16(a, bo[jj], acc[mi][jj], 0, 0, 0);
            }
        }
    }

#pragma unroll
    for (int mi = 0; mi < 4; ++mi) {
#pragma unroll
        for (int jj = 0; jj < 2; ++jj) {
            int col = jbase + jj * 16 + mr;
            float bias = bl[col];
#pragma unroll
            for (int r = 0; r < 4; ++r) {
                int node = node0 + mi * 16 + quad * 4 + r;
                if (node >= n) continue;
                float v = acc[mi][jj][r] + bias;
                if (do_relu) v = fmaxf(v, 0.f);
                outb[(size_t)node * 128 + col] = f2bf(v);
            }
        }
    }
}

// ---------------- pool: one wave per 16-row strip, run-length flush --------
#define POOL_ROWS 16
__global__ __launch_bounds__(256) void k_pool(
    const unsigned short* __restrict__ hb, const int* __restrict__ batch,
    float* __restrict__ gsum, float* __restrict__ gcnt, int n)
{
    int wave = (blockIdx.x * 256 + threadIdx.x) >> 6;
    int lane = threadIdx.x & 63;
    int r0 = wave * POOL_ROWS;
    if (r0 >= n) return;
    int r1 = min(r0 + POOL_ROWS, n);
    int cur = batch[r0];
    float ax = 0.f, ay = 0.f, cnt = 0.f;
    for (int i = r0; i < r1; ++i) {
        int g = batch[i];
        unsigned v = *(const unsigned*)(hb + (size_t)i * 128 + lane * 2);
        if (g != cur) {
            atomicAdd(&gsum[cur * 128 + lane * 2], ax);
            atomicAdd(&gsum[cur * 128 + lane * 2 + 1], ay);
            if (lane == 0) atomicAdd(&gcnt[cur], cnt);
            ax = 0.f; ay = 0.f; cnt = 0.f; cur = g;
        }
        ax += __builtin_bit_cast(float, v << 16);
        ay += __builtin_bit_cast(float, v & 0xffff0000u);
        cnt += 1.f;
    }
    atomicAdd(&gsum[cur * 128 + lane * 2], ax);
    atomicAdd(&gsum[cur * 128 + lane * 2 + 1], ay);
    if (lane == 0) atomicAdd(&gcnt[cur], cnt);
}

__global__ void k_final(const float* __restrict__ gsum, const float* __restrict__ gcnt,
                        const float* __restrict__ Wlin, const float* __restrict__ blin,
                        float* __restrict__ out)
{
    int g = blockIdx.x;   // 64
    int o = threadIdx.x;  // 64
    float inv = 1.f / fmaxf(gcnt[g], 1.f);
    float acc = 0.f;
    for (int k = 0; k < 128; ++k)
        acc += gsum[g * 128 + k] * Wlin[o * 128 + k];
    out[g * 64 + o] = acc * inv + blin[o];
}

extern "C" void kernel_launch(void* const* d_in, const int* in_sizes, int n_in,
                              void* d_out, int out_size, void* d_ws, size_t ws_size,
                              hipStream_t stream) {
    const float* x     = (const float*)d_in[0];
    const int*   ei    = (const int*)d_in[1];
    const int*   batch = (const int*)d_in[2];
    const float* W1l = (const float*)d_in[3];
    const float* b1l = (const float*)d_in[4];
    const float* W1r = (const float*)d_in[5];
    const float* W2l = (const float*)d_in[6];
    const float* b2l = (const float*)d_in[7];
    const float* W2r = (const float*)d_in[8];
    const float* W3l = (const float*)d_in[9];
    const float* b3l = (const float*)d_in[10];
    const float* W3r = (const float*)d_in[11];
    const float* Wlin = (const float*)d_in[12];
    const float* blin = (const float*)d_in[13];

    const int N = in_sizes[2];       // 50000
    const int E = in_sizes[1] / 2;   // 800000
    const int nb = (N + 127) >> 7;   // 391 buckets
    const int epb = (E + BINB - 1) / BINB;  // 5000 edges per bin block

    size_t off = 0;
    auto alloc = [&](size_t bytes) {
        void* p = (char*)d_ws + off;
        off += (bytes + 255) & ~(size_t)255;
        return p;
    };
    int* csr_start = (int*)alloc((size_t)(N + 1) * 4);
    int* cnt       = (int*)alloc((size_t)N * 4);
    int* cnt_mat   = (int*)alloc((size_t)nb * BINB * 4);
    int* off_mat   = (int*)alloc((size_t)nb * BINB * 4);
    int* bsum      = (int*)alloc(256 * 4);
    int* boff      = (int*)alloc(256 * 4);
    int* bsum2     = (int*)alloc(256 * 4);
    int* boff2     = (int*)alloc(256 * 4);
    int* tot_scratch = (int*)alloc(256);
    unsigned short* csr_src = (unsigned short*)alloc((size_t)E * 2);
    unsigned short* x_bf   = (unsigned short*)alloc((size_t)N * 128 * 2);
    unsigned short* hA     = (unsigned short*)alloc((size_t)N * 128 * 2);
    unsigned short* hB     = (unsigned short*)alloc((size_t)N * 128 * 2);
    unsigned short* agg_bf = (unsigned short*)alloc((size_t)N * 128 * 2);
    unsigned char*  h_f8   = (unsigned char*)alloc((size_t)N * 128);
    unsigned short* Whi = (unsigned short*)alloc(3 * 128 * 256 * 2);
    unsigned short* Wlo = (unsigned short*)alloc(3 * 128 * 256 * 2);
    float* gsum = (float*)alloc((size_t)64 * 128 * 4);
    float* gcnt = (float*)alloc((size_t)64 * 4);
    (void)ws_size;

    // binned aliases agg_bf: dead until first k_agg, E*4 <= N*256 bytes.
    unsigned* binned = (unsigned*)agg_bf;

    hipMemsetAsync(gsum, 0, (size_t)64 * 128 * 4, stream);
    hipMemsetAsync(gcnt, 0, (size_t)64 * 4, stream);

    // --- CSR build via bucket counting sort ---
    int nmat = nb * BINB;                  // 62560
    int nscan_m = (nmat + 255) / 256;      // 245
    int nscan_n = (N + 255) / 256;         // 196

    k_bincount<<<BINB, 256, 0, stream>>>(ei + E, cnt_mat, E, nb, epb);
    k_scan1<<<nscan_m, 256, 0, stream>>>(cnt_mat, bsum2, nmat);
    k_scan2<<<1, 256, 0, stream>>>(bsum2, boff2, nscan_m, tot_scratch);
    k_scan3m<<<nscan_m, 256, 0, stream>>>(cnt_mat, boff2, off_mat, nmat);
    k_binscatter<<<BINB, 256, 0, stream>>>(ei, off_mat, binned, E, nb, epb);
    k_hist2<<<nb, 256, 0, stream>>>(binned, off_mat, cnt, E, nb, N);
    k_scan1<<<nscan_n, 256, 0, stream>>>(cnt, bsum, N);
    k_scan2<<<1, 256, 0, stream>>>(bsum, boff, nscan_n, csr_start + N);
    k_scan3m<<<nscan_n, 256, 0, stream>>>(cnt, boff, csr_start, N);
    k_fillfine<<<nb, 256, 0, stream>>>(binned, off_mat, csr_start, csr_src, E, nb, N);

    // Casts
    int n8 = N * 128 / 8;  // 800000
    k_cast_x<<<(n8 + 255) / 256, 256, 0, stream>>>(x, x_bf, h_f8, n8);
    k_cast_w<<<3 * 128, 256, 0, stream>>>(W1l, W1r, W2l, W2r, W3l, W3r, Whi, Wlo);

    int agg_grid = (N + 3) / 4;
    int sage_grid = (N + 63) / 64;

    // Layer 1: x (fp8 gather) -> hA (relu) -> fp8 copy
    k_agg<<<agg_grid, 256, 0, stream>>>(h_f8, csr_start, csr_src, agg_bf, N);
    k_sage<<<sage_grid, 256, 0, stream>>>(agg_bf, x_bf, Whi, Wlo, b1l, hA, N, 1);
    k_cast8<<<(n8 + 255) / 256, 256, 0, stream>>>(hA, h_f8, n8);
    // Layer 2
    k_agg<<<agg_grid, 256, 0, stream>>>(h_f8, csr_start, csr_src, agg_bf, N);
    k_sage<<<sage_grid, 256, 0, stream>>>(agg_bf, hA, Whi + 32768, Wlo + 32768, b2l, hB, N, 1);
    k_cast8<<<(n8 + 255) / 256, 256, 0, stream>>>(hB, h_f8, n8);
    // Layer 3 (no relu, no fp8 copy needed)
    k_agg<<<agg_grid, 256, 0, stream>>>(h_f8, csr_start, csr_src, agg_bf, N);
    k_sage<<<sage_grid, 256, 0, stream>>>(agg_bf, hB, Whi + 65536, Wlo + 65536, b3l, hA, N, 0);

    // Pool + head
    int pool_waves = (N + POOL_ROWS - 1) / POOL_ROWS;
    int pool_blocks = (pool_waves + 3) / 4;
    k_pool<<<pool_blocks, 256, 0, stream>>>(hA, batch, gsum, gcnt, N);
    k_final<<<64, 64, 0, stream>>>(gsum, gcnt, Wlin, blin, (float*)d_out);
}